// Round 1
// baseline (5025.146 us; speedup 1.0000x reference)
//
#include <hip/hip_runtime.h>

// samx_qkv_1bit: per-(b,c) row suffix-automaton retrieval over binary alphabet.
// 1024 independent rows (B*C), each strictly sequential over T=2048 steps.
// Layout decision: one row per workgroup; SAM state in LDS as int16.
//   5 x short[4096] = 40960 B LDS -> exactly 4 blocks/CU on gfx950 (160 KiB/CU),
//   so all 1024 rows are co-resident (256 CU x 4). Proven state bound: a suffix
//   automaton of a length-n string has <= 2n-1 states (n=2048 -> 4095 < 4096).

#define NSTATES 4096
#define TLEN 2048

__global__ __launch_bounds__(64)
void samx_kernel(const float* __restrict__ q,
                 const float* __restrict__ k,
                 const float* __restrict__ v,
                 const float* __restrict__ e,
                 float* __restrict__ out,
                 int T, int C) {
  __shared__ short tr0[NSTATES];  // transition on symbol 0, -1 = absent
  __shared__ short tr1[NSTATES];  // transition on symbol 1
  __shared__ short fl[NSTATES];   // suffix link, -1 = none
  __shared__ short ml[NSTATES];   // max substring length of state
  __shared__ short rl[NSTATES];   // last end position seen, -1 = none

  const int row = blockIdx.x;
  const int b = row / C;
  const int c = row - b * C;

  // Parallel init across the wave, then only lane 0 runs the sequential part.
  for (int s = threadIdx.x; s < NSTATES; s += 64) {
    tr0[s] = -1; tr1[s] = -1; fl[s] = -1; ml[s] = 0; rl[s] = -1;
  }
  __syncthreads();
  if (threadIdx.x != 0) return;

  const size_t rowbase = (size_t)b * (size_t)T * (size_t)C + (size_t)c;
  const float* qr = q + rowbase;
  const float* kr = k + rowbase;
  const float* vr = v + rowbase;
  float* outr = out + rowbase;
  const float epos = e[c];
  const float eneg = -epos;

  int g = 0;  // last state
  int u = 1;  // next free state id
  int w = 0;  // current query-match state
  int h = 0;  // current query-match length

  for (int i = 0; i < T; ++i) {
    const int qs = qr[(size_t)i * C] > 0.0f ? 1 : 0;
    const int ks = kr[(size_t)i * C] > 0.0f ? 1 : 0;
    short* tq = qs ? tr1 : tr0;
    short* tk = ks ? tr1 : tr0;

    // ---- query: extend match with symbol qs, following suffix links ----
    int p = w;
    int x = h;
    int tqp = -1;
    while (p != -1) {
      tqp = tq[p];
      if (tqp != -1) break;
      const int mp = ml[p];
      if (x > mp) x = mp;
      p = fl[p];
    }
    if (p != -1) { p = tqp; x = x + 1; }
    else         { p = 0;   x = 0; }

    // tightest state for match length x
    int vst = p;
    for (;;) {
      const int fv = fl[vst];
      if (fv == -1) break;
      if ((int)ml[fv] < x) break;
      vst = fv;
    }
    // back off to a state with positive length and a recorded endpos
    while (vst != -1 && ((int)ml[vst] <= 0 || (int)rl[vst] < 0)) vst = fl[vst];

    float yval = eneg;  // y=0 -> sign -1
    if (vst != -1) {
      const int pos = (int)rl[vst] + 1;
      if (vr[(size_t)pos * C] > 0.0f) yval = epos;  // yi=1 -> sign +1
    }
    outr[(size_t)i * C] = yval;  // fire-and-forget: off the dependent chain
    w = p; h = x;

    // ---- key: standard suffix-automaton extension with symbol ks ----
    const int j = u++;
    ml[j] = (short)((int)ml[g] + 1);
    p = g;
    int tkp = -1;
    while (p != -1) {
      tkp = tk[p];
      if (tkp != -1) break;
      tk[p] = (short)j;
      p = fl[p];
    }
    if (p == -1) {
      fl[j] = 0;
    } else {
      const int d = tkp;
      if ((int)ml[p] + 1 == (int)ml[d]) {
        fl[j] = (short)d;
      } else {
        const int bb = u++;  // clone
        tr0[bb] = tr0[d];
        tr1[bb] = tr1[d];
        ml[bb] = (short)((int)ml[p] + 1);
        fl[bb] = fl[d];
        rl[bb] = rl[d];
        fl[d] = (short)bb;
        fl[j] = (short)bb;
        while (p != -1 && (int)tk[p] == d) {
          tk[p] = (short)bb;
          p = fl[p];
        }
      }
    }

    // ---- propagate latest end position up the suffix-link chain ----
    g = j;
    int vp = j;
    while (vp != -1 && (int)rl[vp] < i) {
      rl[vp] = (short)i;
      vp = fl[vp];
    }
  }
}

extern "C" void kernel_launch(void* const* d_in, const int* in_sizes, int n_in,
                              void* d_out, int out_size, void* d_ws, size_t ws_size,
                              hipStream_t stream) {
  const float* q = (const float*)d_in[0];
  const float* k = (const float*)d_in[1];
  const float* v = (const float*)d_in[2];
  const float* e = (const float*)d_in[3];
  float* out = (float*)d_out;

  const int C = in_sizes[3];            // e has C elements
  const int T = TLEN;                   // fixed problem shape
  const int B = in_sizes[0] / (T * C);  // q is B*T*C

  dim3 grid(B * C);
  dim3 block(64);
  samx_kernel<<<grid, block, 0, stream>>>(q, k, v, e, out, T, C);
}

// Round 2
// 4468.918 us; speedup vs baseline: 1.1245x; 1.1245x over previous
//
#include <hip/hip_runtime.h>

// samx_qkv_1bit: per-(b,c) row suffix-automaton retrieval over binary alphabet.
// 1024 independent rows (B*C), each strictly sequential over T=2048 steps.
// R2 design:
//  - One row per workgroup (64 threads, 1 wave); SAM state in LDS as int16.
//    5 x short[4096] = 40960 B -> exactly 4 blocks/CU (160 KiB) -> all 1024
//    rows co-resident. State bound: SAM of length-n string has <= 2n-1 states.
//  - q/k streams pre-binarized into per-lane registers (lane L holds bits
//    32L..32L+31 of each stream); the sequential loop reads them with
//    v_readlane (~10 cyc) instead of a cold global load (~400-900 cyc/step).
//  - The loop stores only the retrieval POSITION (u32, fire-and-forget) into
//    d_out; a second fully-parallel kernel gathers v, applies sign*e, and
//    rewrites d_out in place. No vector-memory latency on the dependent chain.

#define NSTATES 4096
#define TLEN 2048

__global__ __launch_bounds__(64)
void samx_main(const float* __restrict__ q,
               const float* __restrict__ k,
               unsigned* __restrict__ outpos,
               int T, int C) {
  __shared__ short tr0[NSTATES];  // transition on symbol 0, -1 = absent
  __shared__ short tr1[NSTATES];  // transition on symbol 1
  __shared__ short fl[NSTATES];   // suffix link, -1 = none
  __shared__ short ml[NSTATES];   // max substring length of state
  __shared__ short rl[NSTATES];   // last end position seen, -1 = none

  const int row = blockIdx.x;
  const int b = row / C;
  const int c = row - b * C;
  const int lane = threadIdx.x;

  // Parallel init of SAM state.
  for (int s = lane; s < NSTATES; s += 64) {
    tr0[s] = -1; tr1[s] = -1; fl[s] = -1; ml[s] = 0; rl[s] = -1;
  }

  const size_t rowbase = (size_t)b * (size_t)T * (size_t)C + (size_t)c;
  const float* qr = q + rowbase;
  const float* kr = k + rowbase;
  unsigned* outr = outpos + rowbase;

  // Pre-binarize q,k: lane L packs bits t = 32L .. 32L+31 (T == 2048 == 64*32).
  unsigned qw = 0u, kw = 0u;
  {
    const int t0 = lane * 32;
#pragma unroll 8
    for (int jj = 0; jj < 32; ++jj) {
      const int t = t0 + jj;
      if (qr[(size_t)t * C] > 0.0f) qw |= (1u << jj);
      if (kr[(size_t)t * C] > 0.0f) kw |= (1u << jj);
    }
  }
  __syncthreads();

  if (lane == 0) {
    int g = 0;  // last state
    int u = 1;  // next free state id
    int w = 0;  // current query-match state
    int h = 0;  // current query-match length

    for (int i = 0; i < T; ++i) {
      const unsigned qwi = (unsigned)__builtin_amdgcn_readlane((int)qw, i >> 5);
      const unsigned kwi = (unsigned)__builtin_amdgcn_readlane((int)kw, i >> 5);
      const int qs = (int)((qwi >> (i & 31)) & 1u);
      const int ks = (int)((kwi >> (i & 31)) & 1u);
      short* tq = qs ? tr1 : tr0;
      short* tk = ks ? tr1 : tr0;

      // ---- query: extend match with symbol qs, following suffix links ----
      int p = w;
      int x = h;
      int tqp = -1;
      while (p != -1) {
        tqp = tq[p];
        if (tqp != -1) break;
        const int mp = ml[p];
        if (x > mp) x = mp;
        p = fl[p];
      }
      if (p != -1) { p = tqp; x = x + 1; }
      else         { p = 0;   x = 0; }

      // tightest state for match length x
      int vst = p;
      for (;;) {
        const int fv = fl[vst];
        if (fv == -1) break;
        if ((int)ml[fv] < x) break;
        vst = fv;
      }
      // back off to a state with positive length and a recorded endpos
      while (vst != -1 && ((int)ml[vst] <= 0 || (int)rl[vst] < 0)) vst = fl[vst];

      unsigned pos = 0xFFFFFFFFu;  // sentinel: no match -> y=0
      if (vst != -1) pos = (unsigned)((int)rl[vst] + 1);
      outr[(size_t)i * C] = pos;  // fire-and-forget; no dependent load
      w = p; h = x;

      // ---- key: standard suffix-automaton extension with symbol ks ----
      const int j = u++;
      ml[j] = (short)((int)ml[g] + 1);
      p = g;
      int tkp = -1;
      while (p != -1) {
        tkp = tk[p];
        if (tkp != -1) break;
        tk[p] = (short)j;
        p = fl[p];
      }
      if (p == -1) {
        fl[j] = 0;
      } else {
        const int d = tkp;
        if ((int)ml[p] + 1 == (int)ml[d]) {
          fl[j] = (short)d;
        } else {
          const int bb = u++;  // clone
          tr0[bb] = tr0[d];
          tr1[bb] = tr1[d];
          ml[bb] = (short)((int)ml[p] + 1);
          fl[bb] = fl[d];
          rl[bb] = rl[d];
          fl[d] = (short)bb;
          fl[j] = (short)bb;
          while (p != -1 && (int)tk[p] == d) {
            tk[p] = (short)bb;
            p = fl[p];
          }
        }
      }

      // ---- propagate latest end position up the suffix-link chain ----
      g = j;
      int vp = j;
      while (vp != -1 && (int)rl[vp] < i) {
        rl[vp] = (short)i;
        vp = fl[vp];
      }
    }
  }
}

// Fully parallel epilogue: read position (u32) from out, gather v, write sign*e.
__global__ __launch_bounds__(256)
void samx_epilogue(const float* __restrict__ v,
                   const float* __restrict__ e,
                   float* __restrict__ out,
                   int T, int C, int total) {
  const int idx = blockIdx.x * 256 + threadIdx.x;
  if (idx >= total) return;
  const unsigned pos = ((const unsigned*)out)[idx];
  const int c = idx % C;
  const int bi = idx / C;  // b*T + i
  const int b = bi / T;
  const float ev = e[c];
  float val = -ev;  // y=0 -> sign -1
  if (pos != 0xFFFFFFFFu) {
    if (v[((size_t)b * (size_t)T + (size_t)pos) * (size_t)C + (size_t)c] > 0.0f)
      val = ev;  // yi=1 -> sign +1
  }
  out[idx] = val;
}

extern "C" void kernel_launch(void* const* d_in, const int* in_sizes, int n_in,
                              void* d_out, int out_size, void* d_ws, size_t ws_size,
                              hipStream_t stream) {
  const float* q = (const float*)d_in[0];
  const float* k = (const float*)d_in[1];
  const float* v = (const float*)d_in[2];
  const float* e = (const float*)d_in[3];

  const int C = in_sizes[3];            // e has C elements
  const int T = TLEN;                   // fixed problem shape
  const int B = in_sizes[0] / (T * C);  // q is B*T*C
  const int total = out_size;

  samx_main<<<dim3(B * C), dim3(64), 0, stream>>>(q, k, (unsigned*)d_out, T, C);
  samx_epilogue<<<dim3((total + 255) / 256), dim3(256), 0, stream>>>(
      v, e, (float*)d_out, T, C, total);
}